// Round 2
// baseline (1081.243 us; speedup 1.0000x reference)
//
#include <hip/hip_runtime.h>

typedef _Float16 half8 __attribute__((ext_vector_type(8)));
typedef _Float16 half2v __attribute__((ext_vector_type(2)));
typedef float floatx4 __attribute__((ext_vector_type(4)));

namespace {
constexpr int RES = 256;
constexpr float SCALE_ = 0.17677669529663687f;  // 1/sqrt(32)
constexpr size_t WT_BYTES = 294912;             // fp16 weights region in ws
constexpr size_t MID_ELEMS = (size_t)4 * 192 * 256 * 256;  // rolled f32 out
}

// ---- prep: transpose+convert weights to fp16 in workspace.
// qkv_wt[col][k] (576 x 192), proj_wt[col][k] (192 x 192).
__global__ void prep_weights(const float* __restrict__ qkv_w,
                             const float* __restrict__ proj_w,
                             _Float16* __restrict__ qkv_wt,
                             _Float16* __restrict__ proj_wt) {
  const int col = blockIdx.x;
  const int k = threadIdx.x;  // 192
  if (col < 576) {
    qkv_wt[col * 192 + k] = (_Float16)qkv_w[(size_t)k * 576 + col];
  } else {
    const int c = col - 576;
    proj_wt[c * 192 + k] = (_Float16)proj_w[(size_t)k * 192 + c];
  }
}

// One block per 8x8 window; 512 threads (8 waves); ~50 KB LDS -> 3 blocks/CU.
// ROLLED=1: store to mid in rolled coords (sector-aligned, full-line merge
// with the adjacent same-XCD window); a separate kernel applies roll(+4,+4).
// ROLLED=0: legacy direct scatter store (fallback if ws too small).
template <bool ROLLED>
__global__ __launch_bounds__(512, 6)
void win_attn_mfma(const float* __restrict__ x,
                   const _Float16* __restrict__ qkv_wt,
                   const float* __restrict__ qkv_b,
                   const _Float16* __restrict__ proj_wt,
                   const float* __restrict__ proj_b,
                   float* __restrict__ ostore) {
  __shared__ _Float16 xs[64][200];  // tokens x channels (A for QKV), 25.6 KB
  __shared__ _Float16 qB[64][40];   // q [tok][d] pre-scaled; REUSED as O_hd  5 KB
  __shared__ _Float16 kB[64][40];   // k [tok][d]                             5 KB
  __shared__ _Float16 vT[32][72];   // v transposed [d][tok]                  4.6 KB
  __shared__ _Float16 st[64][80];   // scores then P, [q][ktok]               10 KB
  __shared__ float rowred[64];      // 1/rowsum

  // XCD-aware bijective swizzle: each XCD gets a contiguous 512-window chunk
  // so horizontally-adjacent windows share an L2 (read lines fetched once,
  // write lines merged).
  const int wid = ((int)blockIdx.x & 7) * 512 + ((int)blockIdx.x >> 3);
  const int b = wid >> 10, wh = (wid >> 5) & 31, ww = wid & 31;
  const int wv = threadIdx.x >> 6;   // wave 0..7
  const int lane = threadIdx.x & 63;
  const int ln = lane & 15;
  const int quad = lane >> 4;
  const int mt = wv >> 1, ng = wv & 1;  // QKV/proj wave tiling

  // ---- Gather rolled (-4,-4) window -> xs[tok][ch] fp16.
#pragma unroll
  for (int t = 0; t < 3; ++t) {
    const int f = threadIdx.x + t * 512;
    const int c2 = (f & 31) + 32 * (f >> 9);   // channel pair 0..95
    const int tg = (f >> 5) & 15;              // token group (4 tokens)
    const int r = tg >> 1;
    const int cw = (tg & 1) * 4;
    const int h = (wh * 8 + r + 4) & (RES - 1);
    const int w0 = (ww * 8 + cw + 4) & (RES - 1);
    const size_t base = (((size_t)b * 192 + c2 * 2) * RES + h) * RES + w0;
    const float4 va = *reinterpret_cast<const float4*>(x + base);
    const float4 vb = *reinterpret_cast<const float4*>(x + base + (size_t)RES * RES);
    const int tok = tg * 4;
    half2v p;
    p[0] = (_Float16)va.x; p[1] = (_Float16)vb.x;
    *(half2v*)&xs[tok + 0][c2 * 2] = p;
    p[0] = (_Float16)va.y; p[1] = (_Float16)vb.y;
    *(half2v*)&xs[tok + 1][c2 * 2] = p;
    p[0] = (_Float16)va.z; p[1] = (_Float16)vb.z;
    *(half2v*)&xs[tok + 2][c2 * 2] = p;
    p[0] = (_Float16)va.w; p[1] = (_Float16)vb.w;
    *(half2v*)&xs[tok + 3][c2 * 2] = p;
  }
  __syncthreads();

  // Projection accumulator, persistent across heads: out = sum_hd O_hd @ Wp_hd
  floatx4 acc6[6];
#pragma unroll
  for (int i = 0; i < 6; ++i) acc6[i] = (floatx4){0.f, 0.f, 0.f, 0.f};

  for (int hd = 0; hd < 6; ++hd) {
    // ---- QKV for this head: 64 x 96 = 4 mtiles x 6 ntiles; wave -> mt, 3 nt.
    {
      int colb[3];
#pragma unroll
      for (int i = 0; i < 3; ++i) {
        const int nt = ng * 3 + i;
        colb[i] = (nt >> 1) * 192 + hd * 32 + (nt & 1) * 16;
      }
      floatx4 acc[3];
#pragma unroll
      for (int i = 0; i < 3; ++i) acc[i] = (floatx4){0.f, 0.f, 0.f, 0.f};
      __builtin_amdgcn_s_setprio(1);
#pragma unroll
      for (int k = 0; k < 6; ++k) {
        const half8 af = *(const half8*)&xs[mt * 16 + ln][k * 32 + quad * 8];
#pragma unroll
        for (int i = 0; i < 3; ++i) {
          const half8 bf = *(const half8*)(qkv_wt +
              (size_t)(colb[i] + ln) * 192 + k * 32 + quad * 8);
          acc[i] = __builtin_amdgcn_mfma_f32_16x16x32_f16(af, bf, acc[i], 0, 0, 0);
        }
      }
      __builtin_amdgcn_s_setprio(0);
#pragma unroll
      for (int i = 0; i < 3; ++i) {
        const int nt = ng * 3 + i;
        const int sec = nt >> 1;  // 0=q 1=k 2=v
        const float bias = qkv_b[colb[i] + ln];
        const int tok0 = mt * 16 + quad * 4;
        const int d = (nt & 1) * 16 + ln;
        if (sec == 0) {
#pragma unroll
          for (int j = 0; j < 4; ++j)
            qB[tok0 + j][d] = (_Float16)((acc[i][j] + bias) * SCALE_);
        } else if (sec == 1) {
#pragma unroll
          for (int j = 0; j < 4; ++j)
            kB[tok0 + j][d] = (_Float16)(acc[i][j] + bias);
        } else {
#pragma unroll
          for (int j = 0; j < 4; ++j)
            vT[d][tok0 + j] = (_Float16)(acc[i][j] + bias);
        }
      }
    }
    __syncthreads();

    // ---- Scores: 16 tiles (4x4), K=32 -> 1 MFMA each; 2 tiles per wave.
#pragma unroll
    for (int i = 0; i < 2; ++i) {
      const int t = wv * 2 + i;
      const int smt = t >> 2, snt = t & 3;
      const half8 aq = *(const half8*)&qB[smt * 16 + ln][quad * 8];
      const half8 bk = *(const half8*)&kB[snt * 16 + ln][quad * 8];
      floatx4 acc = {0.f, 0.f, 0.f, 0.f};
      acc = __builtin_amdgcn_mfma_f32_16x16x32_f16(aq, bk, acc, 0, 0, 0);
      const int r0 = smt * 16 + quad * 4;
#pragma unroll
      for (int j = 0; j < 4; ++j)
        st[r0 + j][snt * 16 + ln] = (_Float16)acc[j];
    }
    __syncthreads();

    // ---- Softmax: row = tid>>3; 8 slices of a row sit in 8 adjacent lanes
    // of one wave -> shuffle reduction, no extra barriers.
    {
      const int row = threadIdx.x >> 3;
      const int sl = threadIdx.x & 7;
      const half8 hv = *(const half8*)&st[row][sl * 8];
      float m = -3.0e38f;
#pragma unroll
      for (int j = 0; j < 8; ++j) m = fmaxf(m, (float)hv[j]);
      m = fmaxf(m, __shfl_xor(m, 1));
      m = fmaxf(m, __shfl_xor(m, 2));
      m = fmaxf(m, __shfl_xor(m, 4));
      float s = 0.f;
      half8 ev;
#pragma unroll
      for (int j = 0; j < 8; ++j) {
        const float e = __expf((float)hv[j] - m);
        s += e;
        ev[j] = (_Float16)e;
      }
      *(half8*)&st[row][sl * 8] = ev;
      s += __shfl_xor(s, 1);
      s += __shfl_xor(s, 2);
      s += __shfl_xor(s, 4);
      if (sl == 0) rowred[row] = 1.0f / s;
    }
    __syncthreads();

    // ---- O_hd = P @ V: 8 tiles (4mt x 2nt); 1 tile per wave. O_hd -> qB.
    {
      const int pmt = wv >> 1, pnt = wv & 1;
      floatx4 acc = {0.f, 0.f, 0.f, 0.f};
#pragma unroll
      for (int ks = 0; ks < 2; ++ks) {
        const half8 ap = *(const half8*)&st[pmt * 16 + ln][ks * 32 + quad * 8];
        const half8 bv = *(const half8*)&vT[pnt * 16 + ln][ks * 32 + quad * 8];
        acc = __builtin_amdgcn_mfma_f32_16x16x32_f16(ap, bv, acc, 0, 0, 0);
      }
      const int tok0 = pmt * 16 + quad * 4;
      const int d = pnt * 16 + ln;
#pragma unroll
      for (int j = 0; j < 4; ++j)
        qB[tok0 + j][d] = (_Float16)(acc[j] * rowred[tok0 + j]);
    }
    __syncthreads();

    // ---- Proj partial: acc6 += O_hd @ proj_w[hd*32 .. hd*32+32, :]; K=32.
    {
      const half8 af = *(const half8*)&qB[mt * 16 + ln][quad * 8];
      __builtin_amdgcn_s_setprio(1);
#pragma unroll
      for (int i = 0; i < 6; ++i) {
        const int c = (ng * 6 + i) * 16 + ln;
        const half8 bf = *(const half8*)(proj_wt +
            (size_t)c * 192 + hd * 32 + quad * 8);
        acc6[i] = __builtin_amdgcn_mfma_f32_16x16x32_f16(af, bf, acc6[i], 0, 0, 0);
      }
      __builtin_amdgcn_s_setprio(0);
    }
    __syncthreads();  // protect qB/kB/vT before next head's QKV writes
  }

  // ---- Epilogue: bias + store.
  // ROLLED: store in rolled coords -> wr = ww*8+cw: 32B-sector-aligned, the
  // 64B line is completed by the adjacent window on the same XCD.
  {
#pragma unroll
    for (int i = 0; i < 6; ++i) {
      const int c = (ng * 6 + i) * 16 + ln;
      const float bias = proj_b[c];
      const int tok0 = mt * 16 + quad * 4;           // 4 consecutive tokens
      const int r = tok0 >> 3, cw = tok0 & 7;        // same window row
      int h, w0;
      if (ROLLED) {
        h = wh * 8 + r;
        w0 = ww * 8 + cw;
      } else {
        h = (wh * 8 + r + 4) & (RES - 1);
        w0 = (ww * 8 + cw + 4) & (RES - 1);
      }
      float4 vv;
      vv.x = acc6[i][0] + bias;
      vv.y = acc6[i][1] + bias;
      vv.z = acc6[i][2] + bias;
      vv.w = acc6[i][3] + bias;
      *reinterpret_cast<float4*>(
          ostore + (((size_t)b * 192 + c) * RES + h) * RES + w0) = vv;
    }
  }
}

// ---- roll(+4,+4) as an exactly-float4-aligned permuted copy (SHIFT==4).
// out[bc][h][w4] = mid[bc][(h-4)&255][(w4-1)&63]   (float4 units in w)
__global__ __launch_bounds__(256)
void roll_back(const float4* __restrict__ mid, float4* __restrict__ out) {
  const size_t idx = (size_t)blockIdx.x * 256 + threadIdx.x;  // < 12,582,912
  const int w4 = (int)(idx & 63);
  const int h = (int)((idx >> 6) & 255);
  const size_t bc = idx >> 14;  // 0..767
  const int hs = (h - 4) & 255;
  const int ws4 = (w4 - 1) & 63;
  out[idx] = mid[(bc << 14) | ((size_t)hs << 6) | (size_t)ws4];
}

extern "C" void kernel_launch(void* const* d_in, const int* in_sizes, int n_in,
                              void* d_out, int out_size, void* d_ws, size_t ws_size,
                              hipStream_t stream) {
  (void)in_sizes; (void)n_in; (void)out_size;
  const float* x      = (const float*)d_in[0];
  const float* qkv_w  = (const float*)d_in[1];
  const float* qkv_b  = (const float*)d_in[2];
  const float* proj_w = (const float*)d_in[3];
  const float* proj_b = (const float*)d_in[4];
  float* out = (float*)d_out;

  _Float16* qkv_wt  = (_Float16*)d_ws;              // 576*192 halfs
  _Float16* proj_wt = qkv_wt + 576 * 192;           // 192*192 halfs

  prep_weights<<<768, 192, 0, stream>>>(qkv_w, proj_w, qkv_wt, proj_wt);

  if (ws_size >= WT_BYTES + MID_ELEMS * sizeof(float)) {
    float* mid = (float*)((char*)d_ws + WT_BYTES);
    win_attn_mfma<true><<<4096, 512, 0, stream>>>(x, qkv_wt, qkv_b, proj_wt,
                                                  proj_b, mid);
    // 12,582,912 float4s / 256 threads
    roll_back<<<49152, 256, 0, stream>>>((const float4*)mid, (float4*)out);
  } else {
    win_attn_mfma<false><<<4096, 512, 0, stream>>>(x, qkv_wt, qkv_b, proj_wt,
                                                   proj_b, out);
  }
}

// Round 3
// 982.162 us; speedup vs baseline: 1.1009x; 1.1009x over previous
//
#include <hip/hip_runtime.h>

typedef _Float16 half8 __attribute__((ext_vector_type(8)));
typedef _Float16 half2v __attribute__((ext_vector_type(2)));
typedef float floatx4 __attribute__((ext_vector_type(4)));

namespace {
constexpr int RES = 256;
constexpr float SCALE_ = 0.17677669529663687f;  // 1/sqrt(32)
constexpr size_t WT_BYTES = 294912;             // fp16 weights region in ws
constexpr size_t NPX = 131072;                  // pixels per 2-batch chunk
constexpr size_t QKV_BYTES = NPX * 576 * 2;     // 150,994,944
constexpr size_t O_BYTES = NPX * 192 * 2;       //  50,331,648
}

// ---- prep: transpose+convert weights to fp16 in workspace.
// qkv_wt[col][k] (576 x 192), proj_wt[col][k] (192 x 192).
__global__ void prep_weights(const float* __restrict__ qkv_w,
                             const float* __restrict__ proj_w,
                             _Float16* __restrict__ qkv_wt,
                             _Float16* __restrict__ proj_wt) {
  const int col = blockIdx.x;
  const int k = threadIdx.x;  // 192
  if (col < 576) {
    qkv_wt[col * 192 + k] = (_Float16)qkv_w[(size_t)k * 576 + col];
  } else {
    const int c = col - 576;
    proj_wt[c * 192 + k] = (_Float16)proj_w[(size_t)k * 192 + c];
  }
}

// ============================================================================
// K_A: QKV GEMM. Tile = 64 w-contiguous pixels at fixed (bb,h). M=64,K=192,
// N=576. One barrier per block. Output qkv[py][576] f16 where py is the
// ROLLED pixel index (py = ((bb*256 + (h-4)&255)*256 + (w-4)&255)), so the
// attention kernel sees windows as contiguous wrap-free rows. q pre-scaled.
// ============================================================================
__global__ __launch_bounds__(512, 4)
void qkv_gemm(const float* __restrict__ x, const _Float16* __restrict__ qkv_wt,
              const float* __restrict__ qkv_b, _Float16* __restrict__ qkv,
              const int b_off) {
  __shared__ _Float16 xs[64][200];  // 64 pixels x 192 ch (+pad), 25.6 KB
  const int pid = blockIdx.x;
  const int w0 = (pid & 3) * 64;
  const int h = (pid >> 2) & (RES - 1);
  const int bb = pid >> 10;
  const int tid = threadIdx.x;

  // stage x -> xs (channel-pair packing; per-instr banks 2-way, free)
#pragma unroll
  for (int t = 0; t < 3; ++t) {
    const int f = tid + t * 512;                // 0..1535
    const int c2 = (f & 31) + 32 * (f >> 9);    // channel pair 0..95
    const int wg = (f >> 5) & 15;               // 4-pixel group along w
    const size_t base =
        (((size_t)(b_off + bb) * 192 + c2 * 2) * RES + h) * RES + w0 + wg * 4;
    const float4 va = *reinterpret_cast<const float4*>(x + base);
    const float4 vb = *reinterpret_cast<const float4*>(x + base + (size_t)RES * RES);
    const int tok = wg * 4;
    half2v p;
    p[0] = (_Float16)va.x; p[1] = (_Float16)vb.x;
    *(half2v*)&xs[tok + 0][c2 * 2] = p;
    p[0] = (_Float16)va.y; p[1] = (_Float16)vb.y;
    *(half2v*)&xs[tok + 1][c2 * 2] = p;
    p[0] = (_Float16)va.z; p[1] = (_Float16)vb.z;
    *(half2v*)&xs[tok + 2][c2 * 2] = p;
    p[0] = (_Float16)va.w; p[1] = (_Float16)vb.w;
    *(half2v*)&xs[tok + 3][c2 * 2] = p;
  }
  __syncthreads();

  const int wv = tid >> 6, lane = tid & 63;
  const int ln = lane & 15, quad = lane >> 4;
  const int mt = wv >> 1, hf = wv & 1;  // wave: 16-pixel stripe x col-half

  half8 af[6];
#pragma unroll
  for (int k = 0; k < 6; ++k)
    af[k] = *(const half8*)&xs[mt * 16 + ln][k * 32 + quad * 8];

  const int rh = (h + RES - 4) & (RES - 1);
  const int rowbase = (bb * RES + rh) * RES;

  for (int i = 0; i < 18; ++i) {               // 18 n-tiles per wave
    const int colb = (hf * 18 + i) * 16;
    floatx4 acc = {0.f, 0.f, 0.f, 0.f};
#pragma unroll
    for (int k = 0; k < 6; ++k) {
      const half8 bf =
          *(const half8*)(qkv_wt + (size_t)(colb + ln) * 192 + k * 32 + quad * 8);
      acc = __builtin_amdgcn_mfma_f32_16x16x32_f16(af[k], bf, acc, 0, 0, 0);
    }
    const float bias = qkv_b[colb + ln];
    const float scl = (colb < 192) ? SCALE_ : 1.0f;  // pre-scale q
#pragma unroll
    for (int j = 0; j < 4; ++j) {
      const int tok = mt * 16 + quad * 4 + j;
      const int rw = (w0 + tok + RES - 4) & (RES - 1);
      qkv[(size_t)(rowbase + rw) * 576 + colb + ln] =
          (_Float16)((acc[j] + bias) * scl);
    }
  }
}

// ============================================================================
// K_B: window attention. One 64-lane wave per (window, head). NO barriers.
// qkv is in rolled pixel order -> window tokens are wrap-free row runs; all
// q/k MFMA fragments are contiguous aligned 16B global loads. V transposed
// through LDS; softmax in-register via 16-lane shuffles; P pre-divided.
// Output O[py][192] f16 (head slice is one aligned 64B line per pixel).
// ============================================================================
__global__ __launch_bounds__(64)
void win_attn(const _Float16* __restrict__ qkv, _Float16* __restrict__ O) {
  __shared__ _Float16 st[64][72];  // P [q][ktok], 9.2 KB
  __shared__ _Float16 vT[32][72];  // V^T [d][ktok], 4.6 KB
  const int wn = blockIdx.x, hd = blockIdx.y;
  const int bb = wn >> 10, wh = (wn >> 5) & 31, ww = wn & 31;
  const int l = threadIdx.x, ln = l & 15, quad = l >> 4;
  const int base = (bb * RES + wh * 8) * RES + ww * 8;  // py of token 0

  // A/B fragments of Q,K: token t = s*16+ln -> py = p0 + s*512
  const int p0 = base + (ln >> 3) * RES + (ln & 7);
  const _Float16* qp = qkv + (size_t)p0 * 576 + hd * 32 + quad * 8;
  half8 qf[4], kf[4];
#pragma unroll
  for (int s = 0; s < 4; ++s) {
    qf[s] = *(const half8*)(qp + (size_t)s * (512 * 576));
    kf[s] = *(const half8*)(qp + (size_t)s * (512 * 576) + 192);
  }

  // V: lane l = token l; transpose into vT[d][tok]
  const int pvx = base + (l >> 3) * RES + (l & 7);
  const _Float16* vp = qkv + (size_t)pvx * 576 + 384 + hd * 32;
  half8 vv[4];
#pragma unroll
  for (int s = 0; s < 4; ++s) vv[s] = *(const half8*)(vp + s * 8);
#pragma unroll
  for (int s = 0; s < 4; ++s)
#pragma unroll
    for (int jj = 0; jj < 8; ++jj) vT[s * 8 + jj][l] = vv[s][jj];

  // scores + in-register softmax, one 16-row stripe at a time
#pragma unroll
  for (int smt = 0; smt < 4; ++smt) {
    floatx4 sc[4];
#pragma unroll
    for (int snt = 0; snt < 4; ++snt) {
      floatx4 z = {0.f, 0.f, 0.f, 0.f};
      sc[snt] = __builtin_amdgcn_mfma_f32_16x16x32_f16(qf[smt], kf[snt], z, 0, 0, 0);
    }
#pragma unroll
    for (int j = 0; j < 4; ++j) {
      float m = fmaxf(fmaxf(sc[0][j], sc[1][j]), fmaxf(sc[2][j], sc[3][j]));
      m = fmaxf(m, __shfl_xor(m, 1));
      m = fmaxf(m, __shfl_xor(m, 2));
      m = fmaxf(m, __shfl_xor(m, 4));
      m = fmaxf(m, __shfl_xor(m, 8));
      const float e0 = __expf(sc[0][j] - m);
      const float e1 = __expf(sc[1][j] - m);
      const float e2 = __expf(sc[2][j] - m);
      const float e3 = __expf(sc[3][j] - m);
      float s = e0 + e1 + e2 + e3;
      s += __shfl_xor(s, 1);
      s += __shfl_xor(s, 2);
      s += __shfl_xor(s, 4);
      s += __shfl_xor(s, 8);
      const float inv = 1.0f / s;
      const int r = smt * 16 + quad * 4 + j;
      st[r][ln] = (_Float16)(e0 * inv);
      st[r][16 + ln] = (_Float16)(e1 * inv);
      st[r][32 + ln] = (_Float16)(e2 * inv);
      st[r][48 + ln] = (_Float16)(e3 * inv);
    }
  }

  // O = P @ V
  half8 bv[2][2];
#pragma unroll
  for (int pnt = 0; pnt < 2; ++pnt)
#pragma unroll
    for (int ks = 0; ks < 2; ++ks)
      bv[pnt][ks] = *(const half8*)&vT[pnt * 16 + ln][ks * 32 + quad * 8];
#pragma unroll
  for (int pmt = 0; pmt < 4; ++pmt) {
    const half8 ap0 = *(const half8*)&st[pmt * 16 + ln][quad * 8];
    const half8 ap1 = *(const half8*)&st[pmt * 16 + ln][32 + quad * 8];
    const int pyr = base + (pmt * 2 + (quad >> 1)) * RES + (quad & 1) * 4;
#pragma unroll
    for (int pnt = 0; pnt < 2; ++pnt) {
      floatx4 acc = {0.f, 0.f, 0.f, 0.f};
      acc = __builtin_amdgcn_mfma_f32_16x16x32_f16(ap0, bv[pnt][0], acc, 0, 0, 0);
      acc = __builtin_amdgcn_mfma_f32_16x16x32_f16(ap1, bv[pnt][1], acc, 0, 0, 0);
#pragma unroll
      for (int j = 0; j < 4; ++j)
        O[(size_t)(pyr + j) * 192 + hd * 32 + pnt * 16 + ln] = (_Float16)acc[j];
    }
  }
}

// ============================================================================
// K_C: projection GEMM + un-roll store. Tile = 64 py-contiguous pixels.
// M=64, N=192, K=192. Zero LDS, zero barriers; A,B direct from global.
// XCD-chunked pid swizzle so w-adjacent tiles share an L2 (store-line merge).
// ============================================================================
__global__ __launch_bounds__(256, 4)
void proj_gemm(const _Float16* __restrict__ O, const _Float16* __restrict__ proj_wt,
               const float* __restrict__ proj_b, float* __restrict__ out,
               const int b_off) {
  const int pid = ((int)blockIdx.x & 7) * 256 + ((int)blockIdx.x >> 3);
  const int rw0 = (pid & 3) * 64;
  const int rh = (pid >> 2) & (RES - 1);
  const int bb = pid >> 10;
  const int tid = threadIdx.x;
  const int mt = tid >> 6, lane = tid & 63;
  const int ln = lane & 15, quad = lane >> 4;
  const int py0 = (bb * RES + rh) * RES + rw0;

  half8 af[6];
#pragma unroll
  for (int k = 0; k < 6; ++k)
    af[k] = *(const half8*)(O + (size_t)(py0 + mt * 16 + ln) * 192 + k * 32 + quad * 8);

  const int h = (rh + 4) & (RES - 1);
  for (int nt = 0; nt < 12; ++nt) {
    const int c = nt * 16 + ln;
    floatx4 acc = {0.f, 0.f, 0.f, 0.f};
#pragma unroll
    for (int k = 0; k < 6; ++k) {
      const half8 bf =
          *(const half8*)(proj_wt + (size_t)c * 192 + k * 32 + quad * 8);
      acc = __builtin_amdgcn_mfma_f32_16x16x32_f16(af[k], bf, acc, 0, 0, 0);
    }
    const float bias = proj_b[c];
    float* op = out + ((size_t)(b_off + bb) * 192 + c) * (RES * RES) + h * RES;
#pragma unroll
    for (int j = 0; j < 4; ++j) {
      const int rw = rw0 + mt * 16 + quad * 4 + j;
      op[(rw + 4) & (RES - 1)] = acc[j] + bias;
    }
  }
}

// ============================================================================
// Fallback: fused single-kernel path (round-1 kernel, direct store). Only
// used if the workspace is too small for the split pipeline.
// ============================================================================
__global__ __launch_bounds__(512, 6)
void win_attn_fused(const float* __restrict__ x,
                    const _Float16* __restrict__ qkv_wt,
                    const float* __restrict__ qkv_b,
                    const _Float16* __restrict__ proj_wt,
                    const float* __restrict__ proj_b,
                    float* __restrict__ out) {
  __shared__ _Float16 xs[64][200];
  __shared__ _Float16 qB[64][40];
  __shared__ _Float16 kB[64][40];
  __shared__ _Float16 vT[32][72];
  __shared__ _Float16 st[64][80];
  __shared__ float rowred[64];

  const int wid = ((int)blockIdx.x & 7) * 512 + ((int)blockIdx.x >> 3);
  const int b = wid >> 10, wh = (wid >> 5) & 31, ww = wid & 31;
  const int wv = threadIdx.x >> 6;
  const int lane = threadIdx.x & 63;
  const int ln = lane & 15;
  const int quad = lane >> 4;
  const int mt = wv >> 1, ng = wv & 1;

#pragma unroll
  for (int t = 0; t < 3; ++t) {
    const int f = threadIdx.x + t * 512;
    const int c2 = (f & 31) + 32 * (f >> 9);
    const int tg = (f >> 5) & 15;
    const int r = tg >> 1;
    const int cw = (tg & 1) * 4;
    const int h = (wh * 8 + r + 4) & (RES - 1);
    const int w0 = (ww * 8 + cw + 4) & (RES - 1);
    const size_t base = (((size_t)b * 192 + c2 * 2) * RES + h) * RES + w0;
    const float4 va = *reinterpret_cast<const float4*>(x + base);
    const float4 vb = *reinterpret_cast<const float4*>(x + base + (size_t)RES * RES);
    const int tok = tg * 4;
    half2v p;
    p[0] = (_Float16)va.x; p[1] = (_Float16)vb.x;
    *(half2v*)&xs[tok + 0][c2 * 2] = p;
    p[0] = (_Float16)va.y; p[1] = (_Float16)vb.y;
    *(half2v*)&xs[tok + 1][c2 * 2] = p;
    p[0] = (_Float16)va.z; p[1] = (_Float16)vb.z;
    *(half2v*)&xs[tok + 2][c2 * 2] = p;
    p[0] = (_Float16)va.w; p[1] = (_Float16)vb.w;
    *(half2v*)&xs[tok + 3][c2 * 2] = p;
  }
  __syncthreads();

  floatx4 acc6[6];
#pragma unroll
  for (int i = 0; i < 6; ++i) acc6[i] = (floatx4){0.f, 0.f, 0.f, 0.f};

  for (int hd = 0; hd < 6; ++hd) {
    {
      int colb[3];
#pragma unroll
      for (int i = 0; i < 3; ++i) {
        const int nt = ng * 3 + i;
        colb[i] = (nt >> 1) * 192 + hd * 32 + (nt & 1) * 16;
      }
      floatx4 acc[3];
#pragma unroll
      for (int i = 0; i < 3; ++i) acc[i] = (floatx4){0.f, 0.f, 0.f, 0.f};
#pragma unroll
      for (int k = 0; k < 6; ++k) {
        const half8 af = *(const half8*)&xs[mt * 16 + ln][k * 32 + quad * 8];
#pragma unroll
        for (int i = 0; i < 3; ++i) {
          const half8 bf = *(const half8*)(qkv_wt +
              (size_t)(colb[i] + ln) * 192 + k * 32 + quad * 8);
          acc[i] = __builtin_amdgcn_mfma_f32_16x16x32_f16(af, bf, acc[i], 0, 0, 0);
        }
      }
#pragma unroll
      for (int i = 0; i < 3; ++i) {
        const int nt = ng * 3 + i;
        const int sec = nt >> 1;
        const float bias = qkv_b[colb[i] + ln];
        const int tok0 = mt * 16 + quad * 4;
        const int d = (nt & 1) * 16 + ln;
        if (sec == 0) {
#pragma unroll
          for (int j = 0; j < 4; ++j)
            qB[tok0 + j][d] = (_Float16)((acc[i][j] + bias) * SCALE_);
        } else if (sec == 1) {
#pragma unroll
          for (int j = 0; j < 4; ++j)
            kB[tok0 + j][d] = (_Float16)(acc[i][j] + bias);
        } else {
#pragma unroll
          for (int j = 0; j < 4; ++j)
            vT[d][tok0 + j] = (_Float16)(acc[i][j] + bias);
        }
      }
    }
    __syncthreads();

#pragma unroll
    for (int i = 0; i < 2; ++i) {
      const int t = wv * 2 + i;
      const int smt = t >> 2, snt = t & 3;
      const half8 aq = *(const half8*)&qB[smt * 16 + ln][quad * 8];
      const half8 bk = *(const half8*)&kB[snt * 16 + ln][quad * 8];
      floatx4 acc = {0.f, 0.f, 0.f, 0.f};
      acc = __builtin_amdgcn_mfma_f32_16x16x32_f16(aq, bk, acc, 0, 0, 0);
      const int r0 = smt * 16 + quad * 4;
#pragma unroll
      for (int j = 0; j < 4; ++j)
        st[r0 + j][snt * 16 + ln] = (_Float16)acc[j];
    }
    __syncthreads();

    {
      const int row = threadIdx.x >> 3;
      const int sl = threadIdx.x & 7;
      const half8 hv = *(const half8*)&st[row][sl * 8];
      float m = -3.0e38f;
#pragma unroll
      for (int j = 0; j < 8; ++j) m = fmaxf(m, (float)hv[j]);
      m = fmaxf(m, __shfl_xor(m, 1));
      m = fmaxf(m, __shfl_xor(m, 2));
      m = fmaxf(m, __shfl_xor(m, 4));
      float s = 0.f;
      half8 ev;
#pragma unroll
      for (int j = 0; j < 8; ++j) {
        const float e = __expf((float)hv[j] - m);
        s += e;
        ev[j] = (_Float16)e;
      }
      *(half8*)&st[row][sl * 8] = ev;
      s += __shfl_xor(s, 1);
      s += __shfl_xor(s, 2);
      s += __shfl_xor(s, 4);
      if (sl == 0) rowred[row] = 1.0f / s;
    }
    __syncthreads();

    {
      const int pmt = wv >> 1, pnt = wv & 1;
      floatx4 acc = {0.f, 0.f, 0.f, 0.f};
#pragma unroll
      for (int ks = 0; ks < 2; ++ks) {
        const half8 ap = *(const half8*)&st[pmt * 16 + ln][ks * 32 + quad * 8];
        const half8 bvv = *(const half8*)&vT[pnt * 16 + ln][ks * 32 + quad * 8];
        acc = __builtin_amdgcn_mfma_f32_16x16x32_f16(ap, bvv, acc, 0, 0, 0);
      }
      const int tok0 = pmt * 16 + quad * 4;
      const int d = pnt * 16 + ln;
#pragma unroll
      for (int j = 0; j < 4; ++j)
        qB[tok0 + j][d] = (_Float16)(acc[j] * rowred[tok0 + j]);
    }
    __syncthreads();

    {
      const half8 af = *(const half8*)&qB[mt * 16 + ln][quad * 8];
#pragma unroll
      for (int i = 0; i < 6; ++i) {
        const int c = (ng * 6 + i) * 16 + ln;
        const half8 bf = *(const half8*)(proj_wt +
            (size_t)c * 192 + hd * 32 + quad * 8);
        acc6[i] = __builtin_amdgcn_mfma_f32_16x16x32_f16(af, bf, acc6[i], 0, 0, 0);
      }
    }
    __syncthreads();
  }

  {
#pragma unroll
    for (int i = 0; i < 6; ++i) {
      const int c = (ng * 6 + i) * 16 + ln;
      const float bias = proj_b[c];
      const int tok0 = mt * 16 + quad * 4;
      const int r = tok0 >> 3, cw = tok0 & 7;
      const int h = (wh * 8 + r + 4) & (RES - 1);
      const int w0 = (ww * 8 + cw + 4) & (RES - 1);
      float4 vv;
      vv.x = acc6[i][0] + bias;
      vv.y = acc6[i][1] + bias;
      vv.z = acc6[i][2] + bias;
      vv.w = acc6[i][3] + bias;
      *reinterpret_cast<float4*>(
          out + (((size_t)b * 192 + c) * RES + h) * RES + w0) = vv;
    }
  }
}

extern "C" void kernel_launch(void* const* d_in, const int* in_sizes, int n_in,
                              void* d_out, int out_size, void* d_ws, size_t ws_size,
                              hipStream_t stream) {
  (void)in_sizes; (void)n_in; (void)out_size;
  const float* x      = (const float*)d_in[0];
  const float* qkv_w  = (const float*)d_in[1];
  const float* qkv_b  = (const float*)d_in[2];
  const float* proj_w = (const float*)d_in[3];
  const float* proj_b = (const float*)d_in[4];
  float* out = (float*)d_out;

  _Float16* qkv_wt  = (_Float16*)d_ws;              // 576*192 halfs
  _Float16* proj_wt = qkv_wt + 576 * 192;           // 192*192 halfs

  prep_weights<<<768, 192, 0, stream>>>(qkv_w, proj_w, qkv_wt, proj_wt);

  if (ws_size >= WT_BYTES + QKV_BYTES + O_BYTES) {
    _Float16* qkv = (_Float16*)((char*)d_ws + WT_BYTES);
    _Float16* Obuf = (_Float16*)((char*)d_ws + WT_BYTES + QKV_BYTES);
    for (int c = 0; c < 2; ++c) {
      const int b_off = c * 2;  // two batches per chunk
      qkv_gemm<<<2048, 512, 0, stream>>>(x, qkv_wt, qkv_b, qkv, b_off);
      win_attn<<<dim3(2048, 6), 64, 0, stream>>>(qkv, Obuf);
      proj_gemm<<<2048, 256, 0, stream>>>(Obuf, proj_wt, proj_b, out, b_off);
    }
  } else {
    win_attn_fused<<<4096, 512, 0, stream>>>(x, qkv_wt, qkv_b, proj_wt,
                                             proj_b, out);
  }
}